// Round 7
// baseline (121.338 us; speedup 1.0000x reference)
//
#include <hip/hip_runtime.h>

// Joint bilateral filter 5x5, SAME zero padding.
// template: (1,3,1080,1920) f32 planar; vector: (1,2,1080,1920) f32 planar.
// out: (1,2,1080,1920) f32 (harness reads non-bf16 outputs as np.float32).
//
// Round 7: I-cache theory. Rounds 2-6 are all-pipes-idle (~25% VALU, ~17%
// HBM) regardless of barrier/residency structure; code size tracks badness
// (r3 ~12KB: 45us, r6 ~28KB straight-line: 54us). L1I is 32KB shared per CU
// cluster; loop-free bodies stream code with zero I$ reuse. This round rolls
// the compute into a small hot loop (~2.3KB executed 8x/wave) and simplifies
// coeff: id>=0 => clip(1-|KVAL-id*SIDIV|,0,1) == max(fma(id,-50,0.875),0)
// (11 ops/tap vs 13). Staging/layout identical to round 6 (proven correct).

#define IMG_H 1080
#define IMG_W 1920
#define IMG_HW (IMG_H * IMG_W)
#define SX 64          // strip width (output px)
#define SY 8           // strip height (output px)
#define WR 12          // window rows  = SY + 4
#define WC 72          // window cols  = SX + 8
#define CH_F (WR * WC) // 864 floats per channel
#define NF4 (CH_F / 4) // 216 float4 slots per channel
#define NCH 5

typedef float f4u __attribute__((ext_vector_type(4), aligned(4)));

__device__ __forceinline__ void loadrow(const float* sm, int off, float w[NCH][8]) {
#pragma unroll
    for (int c = 0; c < NCH; ++c) {
        const float4 a = *(const float4*)(sm + c * CH_F + off);
        const float4 b = *(const float4*)(sm + c * CH_F + off + 4);
        w[c][0] = a.x; w[c][1] = a.y; w[c][2] = a.z; w[c][3] = a.w;
        w[c][4] = b.x; w[c][5] = b.y; w[c][6] = b.z; w[c][7] = b.w;
    }
}

__device__ __forceinline__ void contrib(const float w[NCH][8],
                                        const float c0[4], const float c1[4],
                                        const float c2[4],
                                        float n0[4], float n1[4], float dn[4]) {
#pragma unroll
    for (int dx = 0; dx < 5; ++dx) {
#pragma unroll
        for (int px = 0; px < 4; ++px) {
            const int k = dx + px;
            const float d0 = c0[px] - w[0][k];
            const float d1 = c1[px] - w[1][k];
            const float d2 = c2[px] - w[2][k];
            const float id = d0 * d0 + d1 * d1 + d2 * d2;
            // == clip(1 - |KVAL - id*SIDIV|, 0, 1) since id >= 0
            const float coeff = fmaxf(__builtin_fmaf(id, -50.0f, 0.875f), 0.0f);
            n0[px] += w[3][k] * coeff;
            n1[px] += w[4][k] * coeff;
            dn[px] += coeff;
        }
    }
}

__global__ __launch_bounds__(64)
void jbf_kernel(const float* __restrict__ tpl,
                const float* __restrict__ vec,
                float* __restrict__ out) {
    __shared__ __align__(16) float smem[NCH * CH_F];

    const int lane = threadIdx.x;               // 0..63 (one wave per block)
    const int bx = blockIdx.x, by = blockIdx.y;
    const int x0 = bx * SX, y0 = by * SY;
    const int xs = x0 - 2, ys = y0 - 2;

    const bool interior = (bx >= 1) & (bx <= 28) & (by >= 1) & (by <= 133);

    if (interior) {
        // f4 slot j = i*64 + lane per channel; i<3 full, i==3 lanes 0..23.
        int  off[4];
        bool act[4];
#pragma unroll
        for (int i = 0; i < 4; ++i) {
            const int j = i * 64 + lane;
            act[i] = (j < NF4);
            const int jc = act[i] ? j : 0;
            const int f  = jc * 4;
            const int r  = f / WC;
            const int cc = f - r * WC;
            off[i] = r * IMG_W + cc;
        }
        const int tl = ys * IMG_W + xs;

        f4u v[NCH][4];
#pragma unroll
        for (int c = 0; c < NCH; ++c) {
            const float* __restrict__ src =
                (c < 3) ? (tpl + c * IMG_HW) : (vec + (c - 3) * IMG_HW);
#pragma unroll
            for (int i = 0; i < 4; ++i)
                if (act[i]) v[c][i] = *(const f4u*)(src + tl + off[i]);
        }
#pragma unroll
        for (int c = 0; c < NCH; ++c) {
#pragma unroll
            for (int i = 0; i < 4; ++i) {
                if (act[i]) {
                    const int j = i * 64 + lane;
                    float4 t;
                    t.x = v[c][i].x; t.y = v[c][i].y;
                    t.z = v[c][i].z; t.w = v[c][i].w;
                    *(float4*)&smem[c * CH_F + j * 4] = t;  // 16B-aligned
                }
            }
        }
    } else {
        // border: scalar bounds-checked staging with zero fill (rolled)
#pragma unroll 1
        for (int c = 0; c < NCH; ++c) {
            const float* __restrict__ src =
                (c < 3) ? (tpl + c * IMG_HW) : (vec + (c - 3) * IMG_HW);
#pragma unroll 1
            for (int f = lane; f < CH_F; f += 64) {
                const int r  = f / WC;
                const int cc = f - r * WC;
                const int gy = ys + r;
                const int gx = xs + cc;
                float val = 0.0f;
                if (gy >= 0 && gy < IMG_H && gx >= 0 && gx < IMG_W)
                    val = src[gy * IMG_W + gx];
                smem[c * CH_F + f] = val;
            }
        }
    }
    __syncthreads();   // 1-wave workgroup: compiles to waitcnt only

    // ---- compute: lane owns 4 wide x 2 tall output px; rolled loops ----
    const int tx   = lane & 15;
    const int ty   = lane >> 4;
    const int colb = tx * 4;       // window col of first owned px - 2
    const int rb   = ty * 2;       // window row base
    const int gx   = x0 + colb;

#pragma unroll 1
    for (int s = 0; s < 2; ++s) {
        float n0[4] = {0.f, 0.f, 0.f, 0.f};
        float n1[4] = {0.f, 0.f, 0.f, 0.f};
        float dn[4] = {0.f, 0.f, 0.f, 0.f};
        float w[NCH][8], c0[4], c1[4], c2[4];
        const int base = (rb + s) * WC + colb;   // window row rb+s = dy 0

        // peel dy=2 (center row): extract centers, then contribute
        loadrow(smem, base + 2 * WC, w);
#pragma unroll
        for (int px = 0; px < 4; ++px) {
            c0[px] = w[0][2 + px]; c1[px] = w[1][2 + px]; c2[px] = w[2][2 + px];
        }
        contrib(w, c0, c1, c2, n0, n1, dn);

        // remaining rows dy = 0,1,3,4  (r = it + (it>>1))
#pragma unroll 1
        for (int it = 0; it < 4; ++it) {
            const int r = it + (it >> 1);
            loadrow(smem, base + r * WC, w);
            contrib(w, c0, c1, c2, n0, n1, dn);
        }

        const int gy = y0 + rb + s;
        float4 oa, ob;
        const float r0 = __builtin_amdgcn_rcpf(dn[0]);
        const float r1 = __builtin_amdgcn_rcpf(dn[1]);
        const float r2 = __builtin_amdgcn_rcpf(dn[2]);
        const float r3 = __builtin_amdgcn_rcpf(dn[3]);
        oa.x = n0[0] * r0; oa.y = n0[1] * r1; oa.z = n0[2] * r2; oa.w = n0[3] * r3;
        ob.x = n1[0] * r0; ob.y = n1[1] * r1; ob.z = n1[2] * r2; ob.w = n1[3] * r3;
        *(float4*)(out + (size_t)gy * IMG_W + gx)          = oa;
        *(float4*)(out + IMG_HW + (size_t)gy * IMG_W + gx) = ob;
    }
}

extern "C" void kernel_launch(void* const* d_in, const int* in_sizes, int n_in,
                              void* d_out, int out_size, void* d_ws, size_t ws_size,
                              hipStream_t stream) {
    const float* tpl = (const float*)d_in[0];
    const float* vec = (const float*)d_in[1];
    float* out = (float*)d_out;

    dim3 grid(IMG_W / SX, IMG_H / SY);   // 30 x 135, 64 threads = 1 wave each
    jbf_kernel<<<grid, 64, 0, stream>>>(tpl, vec, out);
}

// Round 8
// 117.719 us; speedup vs baseline: 1.0307x; 1.0307x over previous
//
#include <hip/hip_runtime.h>

// Joint bilateral filter 5x5, SAME zero padding.
// template: (1,3,1080,1920) f32 planar; vector: (1,2,1080,1920) f32 planar.
// out: (1,2,1080,1920) f32 (harness reads non-bf16 outputs as np.float32).
//
// Round 8: zero-LDS register row-sliding. r2-r7 all re-read tap rows from LDS
// per output row (200 B/px) -> shared per-CU LDS pipe + ds_read latency chains
// dominate (4.5M conflict cyc, all pipes <30%). Here one wave owns a 128x8
// strip, streams 12 input rows; each row is loaded ONCE from global (ping-pong
// prefetch, ~1000cyc ahead of use) and contributes to 5 pending output rows
// kept in registers (circular slots). coeff = max(fma(dot,100,fma(T,-50,A)),0)
// with A=fma(S,-50,0.875): algebraic id = S+T-2dot (9 VALU/tap).

#define IMG_H 1080
#define IMG_W 1920
#define IMG_HW (IMG_H * IMG_W)

typedef float f4u __attribute__((ext_vector_type(4), aligned(4)));
typedef float f2u __attribute__((ext_vector_type(2), aligned(8)));

__global__ __launch_bounds__(64)
void jbf_kernel(const float* __restrict__ tpl,
                const float* __restrict__ vec,
                float* __restrict__ out)
{
    const int lane = threadIdx.x;
    const int bx = blockIdx.x, by = blockIdx.y;
    const int x0  = bx * 128;          // 15 strips x 128 = 1920 exact
    const int gy0 = by * 8;            // 135 strips x 8 = 1080 exact
    const int x   = x0 + 2 * lane;     // first of this lane's 2 px
    const bool hborder = (bx == 0) | (bx == 14);

    // per-lane column masks + clamped offsets (constant across rows); window
    // cols x-2 .. x+3 (6 wide: px x needs x-2..x+2, px x+1 needs x-1..x+3)
    float m[6];
    int   co[6];
#pragma unroll
    for (int j = 0; j < 6; ++j) {
        const int c = x - 2 + j;
        m[j]  = (c >= 0 && c < IMG_W) ? 1.0f : 0.0f;
        co[j] = c < 0 ? 0 : (c >= IMG_W ? IMG_W - 1 : c);
    }

    const float* chp[5] = { tpl, tpl + IMG_HW, tpl + 2 * IMG_HW, vec, vec + IMG_HW };

    // 5 pending output-row slots (all compile-time indexed after unroll)
    float sc[5][3][2];                 // centers (3 template ch x 2 px)
    float sA[5][2];                    // A = 0.875 - 50*S
    float n0[5][2], n1[5][2], dn[5][2];
#pragma unroll
    for (int s = 0; s < 5; ++s)
#pragma unroll
        for (int p = 0; p < 2; ++p) {
            sc[s][0][p] = 0.f; sc[s][1][p] = 0.f; sc[s][2][p] = 0.f;
            sA[s][p] = 0.875f; n0[s][p] = 0.f; n1[s][p] = 0.f; dn[s][p] = 0.f;
        }

    float tb[2][5][6];                 // tap-row ping-pong buffers
    float cb[3][2];                    // center prefetch buffer

    auto row_clamp = [](int gr) { return gr < 0 ? 0 : (gr >= IMG_H ? IMG_H - 1 : gr); };

    auto load_tap = [&](int b, int gr) {
        const int rb = row_clamp(gr) * IMG_W;
        if (!hborder) {
#pragma unroll
            for (int c = 0; c < 5; ++c) {
                const float* p = chp[c] + rb + (x - 2);
                const f4u a = *(const f4u*)p;
                const f2u q = *(const f2u*)(p + 4);   // x even -> 8B aligned
                tb[b][c][0] = a.x; tb[b][c][1] = a.y; tb[b][c][2] = a.z;
                tb[b][c][3] = a.w; tb[b][c][4] = q.x; tb[b][c][5] = q.y;
            }
        } else {
#pragma unroll
            for (int c = 0; c < 5; ++c)
#pragma unroll
                for (int j = 0; j < 6; ++j)
                    tb[b][c][j] = chp[c][rb + co[j]];
        }
    };

    auto load_cen = [&](int gr) {       // center cols x,x+1 always in-image
        const int rb = row_clamp(gr) * IMG_W;
#pragma unroll
        for (int c = 0; c < 3; ++c) {
            const f2u v = *(const f2u*)(chp[c] + rb + x);
            cb[c][0] = v.x; cb[c][1] = v.y;
        }
    };

    auto mask_row = [&](int b, bool rowvalid) {
        if (!rowvalid) {                // wave-uniform (top/bottom halo rows)
#pragma unroll
            for (int c = 0; c < 5; ++c)
#pragma unroll
                for (int j = 0; j < 6; ++j) tb[b][c][j] = 0.0f;
        } else if (hborder) {           // wave-uniform (strips 0 and 14)
#pragma unroll
            for (int c = 0; c < 5; ++c)
#pragma unroll
                for (int j = 0; j < 6; ++j) tb[b][c][j] *= m[j];
        }
    };

    auto activate = [&](int s) {        // consume cb -> init slot s
#pragma unroll
        for (int p = 0; p < 2; ++p) {
            const float c0 = cb[0][p], c1 = cb[1][p], c2 = cb[2][p];
            sc[s][0][p] = c0; sc[s][1][p] = c1; sc[s][2][p] = c2;
            const float S = c0 * c0 + c1 * c1 + c2 * c2;
            sA[s][p] = __builtin_fmaf(S, -50.0f, 0.875f);
            n0[s][p] = 0.f; n1[s][p] = 0.f; dn[s][p] = 0.f;
        }
    };

    auto taps = [&](int b) {
        float T[6];
#pragma unroll
        for (int k = 0; k < 6; ++k)
            T[k] = tb[b][0][k] * tb[b][0][k] + tb[b][1][k] * tb[b][1][k]
                 + tb[b][2][k] * tb[b][2][k];
#pragma unroll
        for (int s = 0; s < 5; ++s)
#pragma unroll
            for (int dx = 0; dx < 5; ++dx)
#pragma unroll
                for (int p = 0; p < 2; ++p) {
                    const int k = dx + p;
                    const float dot = sc[s][0][p] * tb[b][0][k]
                                    + sc[s][1][p] * tb[b][1][k]
                                    + sc[s][2][p] * tb[b][2][k];
                    const float B = __builtin_fmaf(T[k], -50.0f, sA[s][p]);
                    const float coeff = fmaxf(__builtin_fmaf(dot, 100.0f, B), 0.0f);
                    n0[s][p] = __builtin_fmaf(tb[b][3][k], coeff, n0[s][p]);
                    n1[s][p] = __builtin_fmaf(tb[b][4][k], coeff, n1[s][p]);
                    dn[s][p] += coeff;
                }
    };

    auto retire = [&](int s, int y) {
        const float r0 = __builtin_amdgcn_rcpf(dn[s][0]);   // den >= 0.875
        const float r1 = __builtin_amdgcn_rcpf(dn[s][1]);
        f2u o0, o1;
        o0.x = n0[s][0] * r0; o0.y = n0[s][1] * r1;
        o1.x = n1[s][0] * r0; o1.y = n1[s][1] * r1;
        *(f2u*)(out + (size_t)y * IMG_W + x) = o0;
        *(f2u*)(out + IMG_HW + (size_t)y * IMG_W + x) = o1;
    };

    // prologue: tap row gy0-2; centers for output row gy0
    load_tap(0, gy0 - 2);
    load_cen(gy0);

#pragma unroll
    for (int r = 0; r < 12; ++r) {
        const int b  = r & 1;
        const int gr = gy0 - 2 + r;                 // current tap row
        if (r < 11) load_tap(1 - b, gr + 1);        // prefetch next tap row
        if (r < 8) {
            activate((r + 4) % 5);                  // output row gy0+r
            if (r < 7) load_cen(gy0 + r + 1);       // prefetch next centers
        }
        const bool rowvalid = (gr >= 0) & (gr < IMG_H);
        mask_row(b, rowvalid);                      // zero-pad semantics
        taps(b);                                    // row -> 5 pending outputs
        if (r >= 4) retire(r % 5, gy0 + r - 4);     // output done after dy=4
    }
}

extern "C" void kernel_launch(void* const* d_in, const int* in_sizes, int n_in,
                              void* d_out, int out_size, void* d_ws, size_t ws_size,
                              hipStream_t stream) {
    const float* tpl = (const float*)d_in[0];
    const float* vec = (const float*)d_in[1];
    float* out = (float*)d_out;

    dim3 grid(IMG_W / 128, IMG_H / 8);   // 15 x 135 waves of 64 threads
    jbf_kernel<<<grid, 64, 0, stream>>>(tpl, vec, out);
}